// Round 1
// baseline (673.160 us; speedup 1.0000x reference)
//
#include <hip/hip_runtime.h>

constexpr int N_ATOMS = 64;
constexpr int NC2 = N_ATOMS * (N_ATOMS - 1) / 2;  // 2016
constexpr int BATCH = 32768;

// One block per batch row. Stage the 2016-float input row in LDS, then emit
// the symmetrized 64x64 matrix with fully coalesced float4 stores.
__global__ __launch_bounds__(256) void triangle_kernel(
    const float* __restrict__ in, float* __restrict__ out) {
    __shared__ float sm[NC2];

    const int b = blockIdx.x;
    const int t = threadIdx.x;

    // --- Stage input row into LDS: 2016 floats = 504 float4 loads ---
    const float4* in4 = reinterpret_cast<const float4*>(in + (size_t)b * NC2);
    float4* sm4 = reinterpret_cast<float4*>(sm);
#pragma unroll
    for (int it = 0; it < 2; ++it) {
        int idx = it * 256 + t;
        if (idx < NC2 / 4) {
            sm4[idx] = in4[idx];
        }
    }
    __syncthreads();

    // --- Write 4096 outputs = 1024 float4 stores, 4 per thread, coalesced ---
    float4* out4 = reinterpret_cast<float4*>(out + (size_t)b * N_ATOMS * N_ATOMS);
#pragma unroll
    for (int it = 0; it < 4; ++it) {
        int e4 = it * 256 + t;      // float4 index in [0, 1024)
        int e = e4 * 4;             // element index in [0, 4096)
        int i = e >> 6;             // row (fixed across the 4 elements)
        int j0 = e & 63;            // first column

        int base_lower = i * (i - 1) / 2;  // start of row i's strict-lower values

        float vv[4];
#pragma unroll
        for (int k = 0; k < 4; ++k) {
            int j = j0 + k;
            float val;
            if (j < i) {
                val = sm[base_lower + j];          // lower triangle: contiguous
            } else if (j > i) {
                val = sm[j * (j - 1) / 2 + i];     // mirrored upper triangle
            } else {
                val = 0.0f;                         // diagonal
            }
            vv[k] = val;
        }
        out4[e4] = make_float4(vv[0], vv[1], vv[2], vv[3]);
    }
}

extern "C" void kernel_launch(void* const* d_in, const int* in_sizes, int n_in,
                              void* d_out, int out_size, void* d_ws, size_t ws_size,
                              hipStream_t stream) {
    const float* in = (const float*)d_in[0];
    float* out = (float*)d_out;
    triangle_kernel<<<BATCH, 256, 0, stream>>>(in, out);
}